// Round 1
// baseline (1360.646 us; speedup 1.0000x reference)
//
#include <hip/hip_runtime.h>
#include <hip/hip_bf16.h>

typedef __bf16 bf16;
typedef __bf16 bf16x8 __attribute__((ext_vector_type(8)));
typedef float  f32x4  __attribute__((ext_vector_type(4)));

#define LDS_STRIDE 40   // 32 + 8 pad (16B) -> breaks ds_read_b128 bank conflicts, keeps 16B align

// ---------------------------------------------------------------------------
// Weight transpose + fp32->bf16 convert: src (K,N) row-major -> dst (N,K)
// ---------------------------------------------------------------------------
__global__ __launch_bounds__(256)
void transpose_cvt(const float* __restrict__ src, bf16* __restrict__ dst, int K, int N)
{
    __shared__ float t[32][33];
    const int bx = blockIdx.x;           // n tile
    const int by = blockIdx.y;           // k tile
    const int tid = threadIdx.x;
    const int c = tid & 31, r0 = tid >> 5;
#pragma unroll
    for (int p = 0; p < 4; p++) {
        int r = r0 + p * 8;
        t[r][c] = src[(size_t)(by * 32 + r) * N + bx * 32 + c];
    }
    __syncthreads();
#pragma unroll
    for (int p = 0; p < 4; p++) {
        int r = r0 + p * 8;
        dst[(size_t)(bx * 32 + r) * K + by * 32 + c] = (bf16)t[c][r];
    }
}

// ---------------------------------------------------------------------------
// 128x128 MFMA GEMM, A (M,K) row-major (fp32 converted in staging, or bf16),
// Bt (N,K) row-major bf16. C = A @ B. Optional second A for concat-K (gate).
// Grid: (N/128, M/128)  -- N fastest so A-tiles are L2/L3-reused across n.
// ---------------------------------------------------------------------------
template<bool ABF16, bool TWOA, bool OUTBF>
__global__ __launch_bounds__(256)
void gemm_bt(const void* __restrict__ Ap, const void* __restrict__ A2p,
             const bf16* __restrict__ Bt, void* __restrict__ Cp,
             int M, int N, int K, int lda, int Ksplit)
{
    __shared__ bf16 Al[128 * LDS_STRIDE];
    __shared__ bf16 Bl[128 * LDS_STRIDE];

    const int tid = threadIdx.x;
    const int n0 = blockIdx.x * 128;
    const int m0 = blockIdx.y * 128;
    const int row = tid >> 1, seg = tid & 1;
    const int wave = tid >> 6, lane = tid & 63;
    const int wm = wave >> 1, wn = wave & 1;
    const int lm = lane & 15, quad = lane >> 4;

    f32x4 acc[4][4];
#pragma unroll
    for (int i = 0; i < 4; i++)
#pragma unroll
        for (int j = 0; j < 4; j++)
#pragma unroll
            for (int r = 0; r < 4; r++) acc[i][j][r] = 0.f;

    for (int k0 = 0; k0 < K; k0 += 32) {
        // ---- stage A tile (128 x 32) ----
        {
            const int kk = k0 + seg * 16;
            bf16x8 u0, u1;
            if (ABF16) {
                const bf16* A = (const bf16*)Ap;
                const bf16* s = A + (size_t)(m0 + row) * lda + kk;
                u0 = *(const bf16x8*)s;
                u1 = *(const bf16x8*)(s + 8);
            } else {
                const float* A = (const float*)Ap;
                int kc = kk;
                if (TWOA && kk >= Ksplit) { A = (const float*)A2p; kc = kk - Ksplit; }
                const float4* s = (const float4*)(A + (size_t)(m0 + row) * lda + kc);
                float4 f0 = s[0], f1 = s[1], f2 = s[2], f3 = s[3];
                u0[0] = (bf16)f0.x; u0[1] = (bf16)f0.y; u0[2] = (bf16)f0.z; u0[3] = (bf16)f0.w;
                u0[4] = (bf16)f1.x; u0[5] = (bf16)f1.y; u0[6] = (bf16)f1.z; u0[7] = (bf16)f1.w;
                u1[0] = (bf16)f2.x; u1[1] = (bf16)f2.y; u1[2] = (bf16)f2.z; u1[3] = (bf16)f2.w;
                u1[4] = (bf16)f3.x; u1[5] = (bf16)f3.y; u1[6] = (bf16)f3.z; u1[7] = (bf16)f3.w;
            }
            *(bf16x8*)&Al[row * LDS_STRIDE + seg * 16]     = u0;
            *(bf16x8*)&Al[row * LDS_STRIDE + seg * 16 + 8] = u1;
        }
        // ---- stage B tile (128 x 32), already bf16, row = n ----
        {
            const bf16* s = Bt + (size_t)(n0 + row) * K + k0 + seg * 16;
            bf16x8 v0 = *(const bf16x8*)s;
            bf16x8 v1 = *(const bf16x8*)(s + 8);
            *(bf16x8*)&Bl[row * LDS_STRIDE + seg * 16]     = v0;
            *(bf16x8*)&Bl[row * LDS_STRIDE + seg * 16 + 8] = v1;
        }
        __syncthreads();

        bf16x8 af[4], bfr[4];
#pragma unroll
        for (int i = 0; i < 4; i++)
            af[i] = *(const bf16x8*)&Al[(wm * 64 + i * 16 + lm) * LDS_STRIDE + quad * 8];
#pragma unroll
        for (int j = 0; j < 4; j++)
            bfr[j] = *(const bf16x8*)&Bl[(wn * 64 + j * 16 + lm) * LDS_STRIDE + quad * 8];
#pragma unroll
        for (int i = 0; i < 4; i++)
#pragma unroll
            for (int j = 0; j < 4; j++)
                acc[i][j] = __builtin_amdgcn_mfma_f32_16x16x32_bf16(af[i], bfr[j], acc[i][j], 0, 0, 0);
        __syncthreads();
    }

    // ---- epilogue: D row = quad*4+reg, col = lane&15 ----
#pragma unroll
    for (int i = 0; i < 4; i++) {
        const int rbase = m0 + wm * 64 + i * 16 + quad * 4;
#pragma unroll
        for (int j = 0; j < 4; j++) {
            const int c = n0 + wn * 64 + j * 16 + lm;
#pragma unroll
            for (int r = 0; r < 4; r++) {
                const float v = acc[i][j][r];
                const size_t idx = (size_t)(rbase + r) * N + c;
                if (OUTBF) ((bf16*)Cp)[idx] = (bf16)v;
                else       ((float*)Cp)[idx] = v;
            }
        }
    }
}

// ---------------------------------------------------------------------------
// Attention over TOPK=8 slots. One wave per (b,h); lane = d in [0,64).
// Q,K,V,Out are chunk-local bf16 buffers, head-major layout h*64+d.
// ---------------------------------------------------------------------------
__global__ __launch_bounds__(256)
void attn_kernel(const bf16* __restrict__ Q, const bf16* __restrict__ Kp,
                 const bf16* __restrict__ Vp, bf16* __restrict__ Out, int nbh)
{
    const int wid = blockIdx.x * 4 + (threadIdx.x >> 6);
    if (wid >= nbh) return;
    const int lane = threadIdx.x & 63;
    const int b = wid >> 4, h = wid & 15;
    const size_t qoff = (size_t)b * 1024 + h * 64 + lane;
    const float q = (float)Q[qoff];

    float vv[8], sc[8];
#pragma unroll
    for (int k = 0; k < 8; k++) {
        const size_t off = ((size_t)(b * 8 + k)) * 1024 + h * 64 + lane;
        const float kk = (float)Kp[off];
        vv[k] = (float)Vp[off];
        float p = q * kk;
        p += __shfl_xor(p, 32);
        p += __shfl_xor(p, 16);
        p += __shfl_xor(p, 8);
        p += __shfl_xor(p, 4);
        p += __shfl_xor(p, 2);
        p += __shfl_xor(p, 1);
        sc[k] = p * 0.125f;          // DH^-0.5 = 1/8
    }
    float mx = sc[0];
#pragma unroll
    for (int k = 1; k < 8; k++) mx = fmaxf(mx, sc[k]);
    float den = 0.f, o = 0.f;
#pragma unroll
    for (int k = 0; k < 8; k++) {
        const float e = __expf(sc[k] - mx);
        den += e;
        o += e * vv[k];
    }
    Out[qoff] = (bf16)(o / den);
}

// ---------------------------------------------------------------------------
// Fused sigmoid gate + residual + LayerNorm. One block (256 thr) per row.
// ---------------------------------------------------------------------------
__global__ __launch_bounds__(256)
void gate_ln_kernel(const float* __restrict__ hs, const float* __restrict__ mo,
                    const float* __restrict__ z,  const float* __restrict__ bg,
                    const float* __restrict__ lng, const float* __restrict__ lnb,
                    float* __restrict__ out)
{
    __shared__ float s1[4], s2[4];
    const int tid = threadIdx.x;
    const size_t base = (size_t)blockIdx.x * 1024 + tid * 4;

    const float4 h4 = *(const float4*)&hs[base];
    const float4 m4 = *(const float4*)&mo[base];
    const float4 z4 = *(const float4*)&z[base];
    const float4 bg4 = *(const float4*)&bg[tid * 4];

    float a[4];
    {
        const float zz0 = z4.x + bg4.x, zz1 = z4.y + bg4.y, zz2 = z4.z + bg4.z, zz3 = z4.w + bg4.w;
        const float g0 = 1.f / (1.f + __expf(-zz0));
        const float g1 = 1.f / (1.f + __expf(-zz1));
        const float g2 = 1.f / (1.f + __expf(-zz2));
        const float g3 = 1.f / (1.f + __expf(-zz3));
        a[0] = h4.x + g0 * m4.x;
        a[1] = h4.y + g1 * m4.y;
        a[2] = h4.z + g2 * m4.z;
        a[3] = h4.w + g3 * m4.w;
    }
    float sum = a[0] + a[1] + a[2] + a[3];
    float sq  = a[0]*a[0] + a[1]*a[1] + a[2]*a[2] + a[3]*a[3];
#pragma unroll
    for (int off = 32; off >= 1; off >>= 1) {
        sum += __shfl_xor(sum, off);
        sq  += __shfl_xor(sq,  off);
    }
    const int wave = tid >> 6;
    if ((tid & 63) == 0) { s1[wave] = sum; s2[wave] = sq; }
    __syncthreads();
    const float ts = s1[0] + s1[1] + s1[2] + s1[3];
    const float tq = s2[0] + s2[1] + s2[2] + s2[3];
    const float mean = ts * (1.f / 1024.f);
    const float var  = tq * (1.f / 1024.f) - mean * mean;
    const float inv  = rsqrtf(var + 1e-5f);

    const float4 g4 = *(const float4*)&lng[tid * 4];
    const float4 b4 = *(const float4*)&lnb[tid * 4];
    float4 o;
    o.x = (a[0] - mean) * inv * g4.x + b4.x;
    o.y = (a[1] - mean) * inv * g4.y + b4.y;
    o.z = (a[2] - mean) * inv * g4.z + b4.z;
    o.w = (a[3] - mean) * inv * g4.w + b4.w;
    *(float4*)&out[base] = o;
}

// ---------------------------------------------------------------------------
extern "C" void kernel_launch(void* const* d_in, const int* in_sizes, int n_in,
                              void* d_out, int out_size, void* d_ws, size_t ws_size,
                              hipStream_t stream)
{
    const float* hs  = (const float*)d_in[0];
    const float* mk  = (const float*)d_in[1];
    const float* mv  = (const float*)d_in[2];
    const float* Wq  = (const float*)d_in[3];
    const float* Wk  = (const float*)d_in[4];
    const float* Wv  = (const float*)d_in[5];
    const float* Wo  = (const float*)d_in[6];
    const float* Wg  = (const float*)d_in[7];
    const float* bg  = (const float*)d_in[8];
    const float* lng = (const float*)d_in[9];
    const float* lnb = (const float*)d_in[10];
    float* out = (float*)d_out;

    const int B = 8192;

    char* ws = (char*)d_ws;
    bf16* Wq_t = (bf16*)(ws + (size_t)0);
    bf16* Wk_t = (bf16*)(ws + ((size_t)2 << 20));
    bf16* Wv_t = (bf16*)(ws + ((size_t)4 << 20));
    bf16* Wo_t = (bf16*)(ws + ((size_t)6 << 20));
    bf16* Wg_t = (bf16*)(ws + ((size_t)8 << 20));
    const size_t WOFF = (size_t)12 << 20;

    const dim3 tb(256);
    transpose_cvt<<<dim3(32, 32), tb, 0, stream>>>(Wq, Wq_t, 1024, 1024);
    transpose_cvt<<<dim3(32, 32), tb, 0, stream>>>(Wk, Wk_t, 1024, 1024);
    transpose_cvt<<<dim3(32, 32), tb, 0, stream>>>(Wv, Wv_t, 1024, 1024);
    transpose_cvt<<<dim3(32, 32), tb, 0, stream>>>(Wo, Wo_t, 1024, 1024);
    transpose_cvt<<<dim3(32, 64), tb, 0, stream>>>(Wg, Wg_t, 2048, 1024);

    // Per-row chunk footprint: Q 2048 + K 16384 + V 16384 + O 2048 + Mo 4096 + Z 4096
    const size_t perRow = 45056;
    const size_t avail = ws_size > WOFF ? ws_size - WOFF : 0;
    long rc = (long)(avail / perRow);
    int Rchunk = (int)((rc / 128) * 128);
    if (Rchunk > B) Rchunk = B;
    if (Rchunk < 128) Rchunk = 128;   // last-resort; needs ~18 MB ws minimum

    char* p = ws + WOFF;
    bf16*  Qb = (bf16*)p;  p += (size_t)Rchunk * 2048;
    bf16*  Kb = (bf16*)p;  p += (size_t)Rchunk * 16384;
    bf16*  Vb = (bf16*)p;  p += (size_t)Rchunk * 16384;
    bf16*  Ob = (bf16*)p;  p += (size_t)Rchunk * 2048;
    float* Mo = (float*)p; p += (size_t)Rchunk * 4096;
    float* Zb = (float*)p;

    for (int off = 0; off < B; off += Rchunk) {
        const int R = (B - off) < Rchunk ? (B - off) : Rchunk;

        // Q = hs @ Wq   (R x 1024, K=1024) -> bf16
        gemm_bt<false, false, true><<<dim3(8, R / 128), tb, 0, stream>>>(
            hs + (size_t)off * 1024, nullptr, Wq_t, Qb, R, 1024, 1024, 1024, 0);
        // K = mk @ Wk   (R*8 x 1024) -> bf16
        gemm_bt<false, false, true><<<dim3(8, R * 8 / 128), tb, 0, stream>>>(
            mk + (size_t)off * 8192, nullptr, Wk_t, Kb, R * 8, 1024, 1024, 1024, 0);
        // V = mv @ Wv   (R*8 x 1024) -> bf16
        gemm_bt<false, false, true><<<dim3(8, R * 8 / 128), tb, 0, stream>>>(
            mv + (size_t)off * 8192, nullptr, Wv_t, Vb, R * 8, 1024, 1024, 1024, 0);
        // attention -> Ob bf16
        attn_kernel<<<dim3(R * 16 / 4), tb, 0, stream>>>(Qb, Kb, Vb, Ob, R * 16);
        // memory_out = Ob @ Wo -> fp32
        gemm_bt<true, false, false><<<dim3(8, R / 128), tb, 0, stream>>>(
            Ob, nullptr, Wo_t, Mo, R, 1024, 1024, 1024, 0);
        // z = hs @ Wg[0:1024] + mo @ Wg[1024:2048] -> fp32 (bg added in LN kernel)
        gemm_bt<false, true, false><<<dim3(8, R / 128), tb, 0, stream>>>(
            hs + (size_t)off * 1024, Mo, Wg_t, Zb, R, 1024, 2048, 1024, 1024);
        // gate + residual + LayerNorm
        gate_ln_kernel<<<dim3(R), tb, 0, stream>>>(
            hs + (size_t)off * 1024, Mo, Zb, bg, lng, lnb, out + (size_t)off * 1024);
    }
}

// Round 2
// 1120.674 us; speedup vs baseline: 1.2141x; 1.2141x over previous
//
#include <hip/hip_runtime.h>
#include <hip/hip_bf16.h>

typedef __bf16 bf16;
typedef __bf16 bf16x8 __attribute__((ext_vector_type(8)));
typedef __bf16 bf16x4 __attribute__((ext_vector_type(4)));
typedef float  f32x4  __attribute__((ext_vector_type(4)));

// ---------------------------------------------------------------------------
// async global->LDS 16B per lane: LDS dst = wave-uniform base + lane*16B
// ---------------------------------------------------------------------------
#if defined(__has_builtin)
#if __has_builtin(__builtin_amdgcn_global_load_lds)
#define HAS_GLD 1
#endif
#endif
#ifndef HAS_GLD
#define HAS_GLD 0
#endif

__device__ __forceinline__ void gld_lds16(const bf16* g, bf16* lds_base)
{
#if HAS_GLD
    __builtin_amdgcn_global_load_lds(
        (const __attribute__((address_space(1))) void*)g,
        (__attribute__((address_space(3))) void*)lds_base, 16, 0, 0);
#else
    *(bf16x8*)(lds_base + (threadIdx.x & 63) * 8) = *(const bf16x8*)g;
#endif
}

// ---------------------------------------------------------------------------
// Weight transpose + fp32->bf16: src (K,N) row-major -> dst (N,K)
// ---------------------------------------------------------------------------
__global__ __launch_bounds__(256)
void transpose_cvt(const float* __restrict__ src, bf16* __restrict__ dst, int K, int N)
{
    __shared__ float t[32][33];
    const int bx = blockIdx.x, by = blockIdx.y, tid = threadIdx.x;
    const int c = tid & 31, r0 = tid >> 5;
#pragma unroll
    for (int p = 0; p < 4; p++) {
        int r = r0 + p * 8;
        t[r][c] = src[(size_t)(by * 32 + r) * N + bx * 32 + c];
    }
    __syncthreads();
#pragma unroll
    for (int p = 0; p < 4; p++) {
        int r = r0 + p * 8;
        dst[(size_t)(bx * 32 + r) * K + by * 32 + c] = (bf16)t[c][r];
    }
}

// ---------------------------------------------------------------------------
// plain fp32 -> bf16 convert, 8 elems/thread
// ---------------------------------------------------------------------------
__global__ __launch_bounds__(256)
void cvt_bf16(const float* __restrict__ src, bf16* __restrict__ dst, int n8)
{
    const int i = blockIdx.x * 256 + threadIdx.x;
    if (i >= n8) return;
    const float4* s = (const float4*)(src + (size_t)i * 8);
    float4 a = s[0], b = s[1];
    bf16x8 o;
    o[0] = (bf16)a.x; o[1] = (bf16)a.y; o[2] = (bf16)a.z; o[3] = (bf16)a.w;
    o[4] = (bf16)b.x; o[5] = (bf16)b.y; o[6] = (bf16)b.z; o[7] = (bf16)b.w;
    *(bf16x8*)(dst + (size_t)i * 8) = o;
}

// ---------------------------------------------------------------------------
// m97-style GEMM: C = A @ B.  A bf16 (rows via ldA), Bt bf16 (N x K, ldB).
// 128x128 tile, BK=32, global_load_lds staging, XCD swizzle (gridDim.x==8).
// Optional A2 for concat-K (gate).  z-dim for per-head offsets.
// ---------------------------------------------------------------------------
template<bool TWOA>
__global__ __launch_bounds__(256)
void gemm_a97(const bf16* __restrict__ A1, const bf16* __restrict__ A2,
              const bf16* __restrict__ Bt, float* __restrict__ Cf,
              bf16* __restrict__ Cb, int Kloop, int Ksplit,
              int ldA, int ldA2, int ldB, int ldC,
              long az, long bz, long cz)
{
    __shared__ bf16 Al[128 * 32];
    __shared__ bf16 Bl[128 * 32];

    const int z = blockIdx.z;
    A1 += (size_t)z * az;
    Bt += (size_t)z * bz;
    if (Cf) Cf += (size_t)z * cz;
    if (Cb) Cb += (size_t)z * cz;

    // XCD swizzle: the 8 n-blocks of one m-tile share flat%8 -> same XCD L2
    int bx, by;
    {
        const int gy = gridDim.y;
        const int flat = blockIdx.y * gridDim.x + blockIdx.x;
        if ((gy & 7) == 0 && gridDim.x == 8) {
            const int xcd = flat & 7, slot = flat >> 3, mpx = gy >> 3;
            by = xcd * mpx + (slot >> 3);
            bx = slot & 7;
        } else { bx = blockIdx.x; by = blockIdx.y; }
    }

    const int tid = threadIdx.x;
    const int wave = tid >> 6, lane = tid & 63;
    const int m0 = by * 128, n0 = bx * 128;
    const int rl = lane >> 2;            // lane's row within 16-row slab
    const int kc = (lane & 3) * 8;       // lane's k-offset within 32-slab
    const int wm = wave >> 1, wn = wave & 1, lm = lane & 15, quad = lane >> 4;

    f32x4 acc[4][4];
#pragma unroll
    for (int i = 0; i < 4; i++)
#pragma unroll
        for (int j = 0; j < 4; j++)
#pragma unroll
            for (int r = 0; r < 4; r++) acc[i][j][r] = 0.f;

    for (int k0 = 0; k0 < Kloop; k0 += 32) {
        const bf16* Ab; int kof, ld;
        if (TWOA && k0 >= Ksplit) { Ab = A2; kof = k0 - Ksplit; ld = ldA2; }
        else                      { Ab = A1; kof = k0;          ld = ldA;  }
        const int r0 = wave * 32 + rl, r1 = r0 + 16;
        gld_lds16(Ab + (size_t)(m0 + r0) * ld + kof + kc, Al + (wave * 32) * 32);
        gld_lds16(Ab + (size_t)(m0 + r1) * ld + kof + kc, Al + (wave * 32 + 16) * 32);
        gld_lds16(Bt + (size_t)(n0 + r0) * ldB + k0 + kc, Bl + (wave * 32) * 32);
        gld_lds16(Bt + (size_t)(n0 + r1) * ldB + k0 + kc, Bl + (wave * 32 + 16) * 32);
        __syncthreads();

        bf16x8 af[4], bfr[4];
#pragma unroll
        for (int i = 0; i < 4; i++)
            af[i] = *(const bf16x8*)&Al[(wm * 64 + i * 16 + lm) * 32 + quad * 8];
#pragma unroll
        for (int j = 0; j < 4; j++)
            bfr[j] = *(const bf16x8*)&Bl[(wn * 64 + j * 16 + lm) * 32 + quad * 8];
#pragma unroll
        for (int i = 0; i < 4; i++)
#pragma unroll
            for (int j = 0; j < 4; j++)
                acc[i][j] = __builtin_amdgcn_mfma_f32_16x16x32_bf16(af[i], bfr[j], acc[i][j], 0, 0, 0);
        __syncthreads();
    }

#pragma unroll
    for (int i = 0; i < 4; i++) {
        const int rbase = m0 + wm * 64 + i * 16 + quad * 4;
#pragma unroll
        for (int j = 0; j < 4; j++) {
            const int c = n0 + wn * 64 + j * 16 + lm;
#pragma unroll
            for (int r = 0; r < 4; r++) {
                const float v = acc[i][j][r];
                const size_t idx = (size_t)(rbase + r) * ldC + c;
                if (Cf) Cf[idx] = v;
                if (Cb) Cb[idx] = (bf16)v;
            }
        }
    }
}

// ---------------------------------------------------------------------------
// N=64 GEMM (out-proj): 256Mx64N tile, 4 waves stacked in M. grid (M/256, 16)
// ---------------------------------------------------------------------------
__global__ __launch_bounds__(256)
void gemm_n64(const bf16* __restrict__ A, const bf16* __restrict__ Bt,
              bf16* __restrict__ C, int ldA, int ldB, int ldC, int Kloop,
              long az, long bz, long cz)
{
    __shared__ bf16 Al[256 * 32];
    __shared__ bf16 Bl[64 * 32];
    const int z = blockIdx.y;
    A  += (size_t)z * az;
    Bt += (size_t)z * bz;
    C  += (size_t)z * cz;

    const int tid = threadIdx.x;
    const int wave = tid >> 6, lane = tid & 63;
    const int m0 = blockIdx.x * 256;
    const int rl = lane >> 2, kc = (lane & 3) * 8;
    const int lm = lane & 15, quad = lane >> 4;

    f32x4 acc[4][4];
#pragma unroll
    for (int i = 0; i < 4; i++)
#pragma unroll
        for (int j = 0; j < 4; j++)
#pragma unroll
            for (int r = 0; r < 4; r++) acc[i][j][r] = 0.f;

    for (int k0 = 0; k0 < Kloop; k0 += 32) {
#pragma unroll
        for (int i = 0; i < 4; i++) {
            const int r = wave * 64 + i * 16 + rl;
            gld_lds16(A + (size_t)(m0 + r) * ldA + k0 + kc, Al + (wave * 64 + i * 16) * 32);
        }
        {
            const int r = wave * 16 + rl;
            gld_lds16(Bt + (size_t)r * ldB + k0 + kc, Bl + (wave * 16) * 32);
        }
        __syncthreads();

        bf16x8 af[4], bfr[4];
#pragma unroll
        for (int i = 0; i < 4; i++)
            af[i] = *(const bf16x8*)&Al[(wave * 64 + i * 16 + lm) * 32 + quad * 8];
#pragma unroll
        for (int j = 0; j < 4; j++)
            bfr[j] = *(const bf16x8*)&Bl[(j * 16 + lm) * 32 + quad * 8];
#pragma unroll
        for (int i = 0; i < 4; i++)
#pragma unroll
            for (int j = 0; j < 4; j++)
                acc[i][j] = __builtin_amdgcn_mfma_f32_16x16x32_bf16(af[i], bfr[j], acc[i][j], 0, 0, 0);
        __syncthreads();
    }

#pragma unroll
    for (int i = 0; i < 4; i++) {
        const int rbase = m0 + wave * 64 + i * 16 + quad * 4;
#pragma unroll
        for (int j = 0; j < 4; j++) {
            const int c = j * 16 + lm;
#pragma unroll
            for (int r = 0; r < 4; r++)
                C[(size_t)(rbase + r) * ldC + c] = (bf16)acc[i][j][r];
        }
    }
}

// ---------------------------------------------------------------------------
// Fused attention: scores = U . mk / 8 -> softmax -> W_mix = attn . mv
// One block per row b.  U (16,1024) bf16; mk,mv (8,1024) fp32 raw inputs.
// ---------------------------------------------------------------------------
#define MLD 1032   // padded mk-row stride (bf16 elems): +8 breaks 8-way bank conflict
__global__ __launch_bounds__(256)
void attn_umix(const bf16* __restrict__ U, const float* __restrict__ mk,
               const float* __restrict__ mv, bf16* __restrict__ Wm)
{
    __shared__ bf16 Ul[16 * 1024];
    __shared__ bf16 Ml[8 * MLD];
    __shared__ bf16 Vl[8 * 1024];
    __shared__ float Sc[128], E[128], Inv[16];

    const int b = blockIdx.x, t = threadIdx.x;
    const bf16*  Ub  = U  + (size_t)b * 16384;
    const float* mkb = mk + (size_t)b * 8192;
    const float* mvb = mv + (size_t)b * 8192;

    // stage U (bf16 straight copy)
    for (int i = t; i < 2048; i += 256)
        *(bf16x8*)&Ul[i * 8] = *(const bf16x8*)&Ub[i * 8];
    // stage mk, mv with fp32->bf16 convert
    for (int g = t; g < 1024; g += 256) {
        const int k = g >> 7, c = (g & 127) * 8;
        const float4* s = (const float4*)(mkb + k * 1024 + c);
        float4 a = s[0], d = s[1];
        bf16x8 o;
        o[0] = (bf16)a.x; o[1] = (bf16)a.y; o[2] = (bf16)a.z; o[3] = (bf16)a.w;
        o[4] = (bf16)d.x; o[5] = (bf16)d.y; o[6] = (bf16)d.z; o[7] = (bf16)d.w;
        *(bf16x8*)&Ml[k * MLD + c] = o;
        const float4* s2 = (const float4*)(mvb + k * 1024 + c);
        float4 a2 = s2[0], d2 = s2[1];
        bf16x8 o2;
        o2[0] = (bf16)a2.x; o2[1] = (bf16)a2.y; o2[2] = (bf16)a2.z; o2[3] = (bf16)a2.w;
        o2[4] = (bf16)d2.x; o2[5] = (bf16)d2.y; o2[6] = (bf16)d2.z; o2[7] = (bf16)d2.w;
        *(bf16x8*)&Vl[k * 1024 + c] = o2;
    }
    __syncthreads();

    // scores: 128 (h,k) pairs x 2 threads, each sums 512 i's
    {
        const int pair = t >> 1, half = t & 1;
        const int h = pair >> 3, k = pair & 7;
        float s = 0.f;
        const int i0 = half * 512;
#pragma unroll 4
        for (int i = i0; i < i0 + 512; i += 8) {
            bf16x8 u = *(const bf16x8*)&Ul[h * 1024 + i];
            bf16x8 m = *(const bf16x8*)&Ml[k * MLD + i];
#pragma unroll
            for (int j = 0; j < 8; j++) s += (float)u[j] * (float)m[j];
        }
        s += __shfl_xor(s, 1);
        if (half == 0) Sc[pair] = s * 0.125f;
    }
    __syncthreads();

    if (t < 16) {
        float mx = Sc[t * 8];
#pragma unroll
        for (int k = 1; k < 8; k++) mx = fmaxf(mx, Sc[t * 8 + k]);
        float den = 0.f;
#pragma unroll
        for (int k = 0; k < 8; k++) { float e = __expf(Sc[t * 8 + k] - mx); E[t * 8 + k] = e; den += e; }
        Inv[t] = 1.f / den;
    }
    __syncthreads();

    // W_mix[h][i] = Inv[h] * sum_k E[h][k] * Vl[k][i]
    {
        const int h = t >> 4;
        const float inv = Inv[h];
        float ev[8];
#pragma unroll
        for (int k = 0; k < 8; k++) ev[k] = E[h * 8 + k] * inv;
        bf16* dst = Wm + (size_t)b * 16384 + h * 1024;
#pragma unroll
        for (int c = 0; c < 8; c++) {
            const int i = (t & 15) * 8 + c * 128;
            float o[8] = {0, 0, 0, 0, 0, 0, 0, 0};
#pragma unroll
            for (int k = 0; k < 8; k++) {
                bf16x8 v = *(const bf16x8*)&Vl[k * 1024 + i];
#pragma unroll
                for (int j = 0; j < 8; j++) o[j] += ev[k] * (float)v[j];
            }
            bf16x8 ob;
#pragma unroll
            for (int j = 0; j < 8; j++) ob[j] = (bf16)o[j];
            *(bf16x8*)&dst[i] = ob;
        }
    }
}

// ---------------------------------------------------------------------------
// sigmoid gate + residual + LayerNorm. One block per row.
// ---------------------------------------------------------------------------
__global__ __launch_bounds__(256)
void gate_ln_kernel(const float* __restrict__ hs, const float* __restrict__ mo,
                    const float* __restrict__ z,  const float* __restrict__ bg,
                    const float* __restrict__ lng, const float* __restrict__ lnb,
                    float* __restrict__ out)
{
    __shared__ float s1[4], s2[4];
    const int tid = threadIdx.x;
    const size_t base = (size_t)blockIdx.x * 1024 + tid * 4;

    const float4 h4 = *(const float4*)&hs[base];
    const float4 m4 = *(const float4*)&mo[base];
    const float4 z4 = *(const float4*)&z[base];
    const float4 bg4 = *(const float4*)&bg[tid * 4];

    float a[4];
    {
        const float g0 = 1.f / (1.f + __expf(-(z4.x + bg4.x)));
        const float g1 = 1.f / (1.f + __expf(-(z4.y + bg4.y)));
        const float g2 = 1.f / (1.f + __expf(-(z4.z + bg4.z)));
        const float g3 = 1.f / (1.f + __expf(-(z4.w + bg4.w)));
        a[0] = h4.x + g0 * m4.x;
        a[1] = h4.y + g1 * m4.y;
        a[2] = h4.z + g2 * m4.z;
        a[3] = h4.w + g3 * m4.w;
    }
    float sum = a[0] + a[1] + a[2] + a[3];
    float sq  = a[0]*a[0] + a[1]*a[1] + a[2]*a[2] + a[3]*a[3];
#pragma unroll
    for (int off = 32; off >= 1; off >>= 1) {
        sum += __shfl_xor(sum, off);
        sq  += __shfl_xor(sq,  off);
    }
    const int wave = tid >> 6;
    if ((tid & 63) == 0) { s1[wave] = sum; s2[wave] = sq; }
    __syncthreads();
    const float mean = (s1[0] + s1[1] + s1[2] + s1[3]) * (1.f / 1024.f);
    const float var  = (s2[0] + s2[1] + s2[2] + s2[3]) * (1.f / 1024.f) - mean * mean;
    const float inv  = rsqrtf(var + 1e-5f);

    const float4 g4 = *(const float4*)&lng[tid * 4];
    const float4 b4 = *(const float4*)&lnb[tid * 4];
    float4 o;
    o.x = (a[0] - mean) * inv * g4.x + b4.x;
    o.y = (a[1] - mean) * inv * g4.y + b4.y;
    o.z = (a[2] - mean) * inv * g4.z + b4.z;
    o.w = (a[3] - mean) * inv * g4.w + b4.w;
    *(float4*)&out[base] = o;
}

// ---------------------------------------------------------------------------
extern "C" void kernel_launch(void* const* d_in, const int* in_sizes, int n_in,
                              void* d_out, int out_size, void* d_ws, size_t ws_size,
                              hipStream_t stream)
{
    const float* hs  = (const float*)d_in[0];
    const float* mk  = (const float*)d_in[1];
    const float* mv  = (const float*)d_in[2];
    const float* Wq  = (const float*)d_in[3];
    const float* Wk  = (const float*)d_in[4];
    const float* Wv  = (const float*)d_in[5];
    const float* Wo  = (const float*)d_in[6];
    const float* Wg  = (const float*)d_in[7];
    const float* bg  = (const float*)d_in[8];
    const float* lng = (const float*)d_in[9];
    const float* lnb = (const float*)d_in[10];
    float* out = (float*)d_out;

    const int B = 8192;
    const dim3 tb(256);

    char* ws = (char*)d_ws;
    bf16* Wq_t = (bf16*)(ws);                      // 2 MB  (1024x1024, N x K)
    bf16* Wv_t = (bf16*)(ws + ((size_t)2 << 20));  // 2 MB
    bf16* Wo_t = (bf16*)(ws + ((size_t)4 << 20));  // 2 MB
    bf16* Wg_t = (bf16*)(ws + ((size_t)6 << 20));  // 4 MB  (1024x2048)
    bf16* Wk_b = (bf16*)(ws + ((size_t)10 << 20)); // 2 MB  (1024x1024, NOT transposed)
    bf16* hs_b = (bf16*)(ws + ((size_t)12 << 20)); // 16 MB (8192x1024)
    const size_t CBASE = (size_t)28 << 20;

    transpose_cvt<<<dim3(32, 32), tb, 0, stream>>>(Wq, Wq_t, 1024, 1024);
    transpose_cvt<<<dim3(32, 32), tb, 0, stream>>>(Wv, Wv_t, 1024, 1024);
    transpose_cvt<<<dim3(32, 32), tb, 0, stream>>>(Wo, Wo_t, 1024, 1024);
    transpose_cvt<<<dim3(32, 64), tb, 0, stream>>>(Wg, Wg_t, 2048, 1024);
    cvt_bf16<<<dim3(1024 * 1024 / 8 / 256), tb, 0, stream>>>(Wk, Wk_b, 1024 * 1024 / 8);
    cvt_bf16<<<dim3(B * 1024 / 8 / 256), tb, 0, stream>>>(hs, hs_b, B * 1024 / 8);

    // chunk size: multiple of 1024, capped at 4096 (keeps U/W_mix L3-resident)
    const size_t perRow = 2048 + 32768 + 32768 + 2048 + 4096 + 2048 + 4096; // 79872
    const size_t avail = ws_size > CBASE ? ws_size - CBASE : 0;
    long rc = (long)(avail / perRow);
    int Rchunk = (int)((rc / 1024) * 1024);
    if (Rchunk > 4096) Rchunk = 4096;
    if (Rchunk < 1024) Rchunk = 1024;

    char* p = ws + CBASE;
    bf16*  Qb   = (bf16*)p;  p += (size_t)Rchunk * 2048;
    bf16*  Ub   = (bf16*)p;  p += (size_t)Rchunk * 32768;
    bf16*  Wm   = (bf16*)p;  p += (size_t)Rchunk * 32768;
    bf16*  OH   = (bf16*)p;  p += (size_t)Rchunk * 2048;
    float* Mo   = (float*)p; p += (size_t)Rchunk * 4096;
    bf16*  Mo_b = (bf16*)p;  p += (size_t)Rchunk * 2048;
    float* Zb   = (float*)p;

    for (int off = 0; off < B; off += Rchunk) {
        const int R = (B - off) < Rchunk ? (B - off) : Rchunk;

        // Q = hs @ Wq -> bf16 (R x 1024)
        gemm_a97<false><<<dim3(8, R / 128, 1), tb, 0, stream>>>(
            hs_b + (size_t)off * 1024, nullptr, Wq_t, nullptr, Qb,
            1024, 1024, 1024, 0, 1024, 1024, 0, 0, 0);
        // U[b,h,:] = Q_h @ Wk_h^T : 16 heads, K=64 -> bf16 (R x 16 x 1024)
        gemm_a97<false><<<dim3(8, R / 128, 16), tb, 0, stream>>>(
            Qb, nullptr, Wk_b, nullptr, Ub,
            64, 64, 1024, 0, 1024, 16384, 64, 64, 1024);
        // fused attention: scores/softmax/mix on raw fp32 mk/mv
        attn_umix<<<dim3(R), tb, 0, stream>>>(
            Ub, mk + (size_t)off * 8192, mv + (size_t)off * 8192, Wm);
        // out_heads = W_mix_h @ Wv_h : 16 heads, N=64 -> bf16 (R x 1024)
        gemm_n64<<<dim3(R / 256, 16), tb, 0, stream>>>(
            Wm, Wv_t, OH, 16384, 1024, 1024, 1024,
            1024, (long)64 * 1024, 64);
        // memory_out = OH @ Wo -> fp32 Mo + bf16 Mo_b
        gemm_a97<false><<<dim3(8, R / 128, 1), tb, 0, stream>>>(
            OH, nullptr, Wo_t, Mo, Mo_b,
            1024, 1024, 1024, 0, 1024, 1024, 0, 0, 0);
        // z = [hs, Mo] @ Wg -> fp32
        gemm_a97<true><<<dim3(8, R / 128, 1), tb, 0, stream>>>(
            hs_b + (size_t)off * 1024, Mo_b, Wg_t, Zb, nullptr,
            2048, 1024, 1024, 1024, 2048, 1024, 0, 0, 0);
        // gate + residual + LayerNorm
        gate_ln_kernel<<<dim3(R), tb, 0, stream>>>(
            hs + (size_t)off * 1024, Mo, Zb, bg, lng, lnb, out + (size_t)off * 1024);
    }
}